// Round 1
// baseline (4343.761 us; speedup 1.0000x reference)
//
#include <hip/hip_runtime.h>
#include <hip/hip_bf16.h>
#include <math.h>

#define LN   2048
#define IDM  1024
#define ODM  1024
#define NB   8
#define NEG_SLOPE 0.2f

// ---------------------------------------------------------------------------
// Tiled fp32 GEMM (vector ALU; CDNA4 has no fp32 MFMA).
// C[M,N] = A[M,K] @ B   (BT=0: B is [K,N] row-major; BT=1: B is [N,K] row-major, i.e. C=A*B^T)
// EPI: 0 = plain store, 1 = + extra[row,col] (residual), 2 = leaky_relu + extra[row & (LN-1), col] (bias)
// Tile 64x64, block 256 threads, 4x4 microtile/thread, K-step 16.
// ---------------------------------------------------------------------------
template<int BT, int EPI>
__global__ __launch_bounds__(256) void gemm_f32(
    const float* __restrict__ A, const float* __restrict__ Bm,
    const float* __restrict__ extra, float* __restrict__ C,
    int M, int N, int K)
{
    __shared__ float As[16][68];   // [kk][m], stride 68 -> 2-way max bank alias
    __shared__ float Bs[16][68];   // [kk][n]

    const int tid = threadIdx.x;
    const int m0 = blockIdx.y * 64;
    const int n0 = blockIdx.x * 64;
    const int tm = tid & 15;       // 0..15 -> 4 rows each
    const int tn = tid >> 4;       // 0..15 -> 4 cols each

    const int lr = tid >> 2;        // 0..63 (tile row for strided loads)
    const int lc = (tid & 3) * 4;   // 0,4,8,12 (k-offset)

    float acc[4][4] = {};

    for (int k0 = 0; k0 < K; k0 += 16) {
        __syncthreads();
        // A tile: A[m0+lr][k0+lc..+3] -> As[lc+j][lr]
        {
            float4 a4 = *(const float4*)&A[(size_t)(m0 + lr) * K + (k0 + lc)];
            As[lc + 0][lr] = a4.x;
            As[lc + 1][lr] = a4.y;
            As[lc + 2][lr] = a4.z;
            As[lc + 3][lr] = a4.w;
        }
        if (BT == 0) {
            // B tile: B[k0+br][n0+bc..+3] -> Bs[br][bc]
            const int br = tid >> 4;        // 0..15
            const int bc = (tid & 15) * 4;  // 0..60
            float4 b4 = *(const float4*)&Bm[(size_t)(k0 + br) * N + (n0 + bc)];
            *(float4*)&Bs[br][bc] = b4;
        } else {
            // B tile (transposed use): B[n0+lr][k0+lc..+3] -> Bs[lc+j][lr]
            float4 b4 = *(const float4*)&Bm[(size_t)(n0 + lr) * K + (k0 + lc)];
            Bs[lc + 0][lr] = b4.x;
            Bs[lc + 1][lr] = b4.y;
            Bs[lc + 2][lr] = b4.z;
            Bs[lc + 3][lr] = b4.w;
        }
        __syncthreads();

        #pragma unroll
        for (int kk = 0; kk < 16; ++kk) {
            float4 av = *(const float4*)&As[kk][tm * 4];
            float4 bv = *(const float4*)&Bs[kk][tn * 4];
            const float* ap = (const float*)&av;
            const float* bp = (const float*)&bv;
            #pragma unroll
            for (int mi = 0; mi < 4; ++mi)
                #pragma unroll
                for (int ni = 0; ni < 4; ++ni)
                    acc[mi][ni] = fmaf(ap[mi], bp[ni], acc[mi][ni]);
        }
    }

    // epilogue: each thread writes 4 rows x float4
    #pragma unroll
    for (int mi = 0; mi < 4; ++mi) {
        const int row = m0 + tm * 4 + mi;
        const int col = n0 + tn * 4;
        float4 r;
        r.x = acc[mi][0]; r.y = acc[mi][1]; r.z = acc[mi][2]; r.w = acc[mi][3];
        if (EPI == 1) {
            float4 e = *(const float4*)&extra[(size_t)row * N + col];
            r.x += e.x; r.y += e.y; r.z += e.z; r.w += e.w;
        } else if (EPI == 2) {
            r.x = (r.x >= 0.f) ? r.x : NEG_SLOPE * r.x;
            r.y = (r.y >= 0.f) ? r.y : NEG_SLOPE * r.y;
            r.z = (r.z >= 0.f) ? r.z : NEG_SLOPE * r.z;
            r.w = (r.w >= 0.f) ? r.w : NEG_SLOPE * r.w;
            float4 e = *(const float4*)&extra[(size_t)(row & (LN - 1)) * N + col];
            r.x += e.x; r.y += e.y; r.z += e.z; r.w += e.w;
        }
        *(float4*)&C[(size_t)row * N + col] = r;
    }
}

// ---------------------------------------------------------------------------
// Row softmax over [nrows x 2048], one block (256 thr) per row.
// ---------------------------------------------------------------------------
__global__ __launch_bounds__(256) void softmax_rows(float* __restrict__ S)
{
    const int tid = threadIdx.x;
    float* row = S + (size_t)blockIdx.x * LN;

    float4 v0 = *(const float4*)&row[tid * 4];
    float4 v1 = *(const float4*)&row[1024 + tid * 4];

    float m = fmaxf(fmaxf(fmaxf(v0.x, v0.y), fmaxf(v0.z, v0.w)),
                    fmaxf(fmaxf(v1.x, v1.y), fmaxf(v1.z, v1.w)));
    #pragma unroll
    for (int off = 32; off > 0; off >>= 1) m = fmaxf(m, __shfl_xor(m, off));

    __shared__ float red[8];
    if ((tid & 63) == 0) red[tid >> 6] = m;
    __syncthreads();
    m = fmaxf(fmaxf(red[0], red[1]), fmaxf(red[2], red[3]));

    float e[8];
    e[0] = expf(v0.x - m); e[1] = expf(v0.y - m); e[2] = expf(v0.z - m); e[3] = expf(v0.w - m);
    e[4] = expf(v1.x - m); e[5] = expf(v1.y - m); e[6] = expf(v1.z - m); e[7] = expf(v1.w - m);
    float s = ((e[0] + e[1]) + (e[2] + e[3])) + ((e[4] + e[5]) + (e[6] + e[7]));
    #pragma unroll
    for (int off = 32; off > 0; off >>= 1) s += __shfl_xor(s, off);
    if ((tid & 63) == 0) red[4 + (tid >> 6)] = s;
    __syncthreads();
    s = (red[4] + red[5]) + (red[6] + red[7]);

    const float inv = 1.0f / s;
    v0.x = e[0] * inv; v0.y = e[1] * inv; v0.z = e[2] * inv; v0.w = e[3] * inv;
    v1.x = e[4] * inv; v1.y = e[5] * inv; v1.z = e[6] * inv; v1.w = e[7] * inv;
    *(float4*)&row[tid * 4] = v0;
    *(float4*)&row[1024 + tid * 4] = v1;
}

// ---------------------------------------------------------------------------
extern "C" void kernel_launch(void* const* d_in, const int* in_sizes, int n_in,
                              void* d_out, int out_size, void* d_ws, size_t ws_size,
                              hipStream_t stream)
{
    (void)in_sizes; (void)n_in; (void)out_size;
    const float* i_in  = (const float*)d_in[0];  // [NB, LN, IDM]
    const float* k_w   = (const float*)d_in[1];  // [IDM, IDM]
    const float* q_w   = (const float*)d_in[2];  // [IDM, IDM]
    const float* v_w   = (const float*)d_in[3];  // [IDM, IDM]
    const float* mlp_w = (const float*)d_in[4];  // [IDM, ODM]
    const float* bias  = (const float*)d_in[5];  // [LN, ODM]
    float* out = (float*)d_out;                  // [NB, LN, ODM]

    char* ws = (char*)d_ws;
    const size_t FB  = (size_t)NB * LN * IDM * sizeof(float);  // 64 MiB full-batch buf
    const size_t SB  = (size_t)LN * LN * sizeof(float);        // 16 MiB scores buf
    const size_t PB  = (size_t)LN * IDM * sizeof(float);       // 8 MiB per-batch buf

    const dim3 blk(256);

    if (ws_size >= 4 * FB + SB) {
        // ---- big path: full-batch QKV / ret, per-batch scores (reused) ----
        float* Q   = (float*)(ws);
        float* Kb  = (float*)(ws + FB);
        float* V   = (float*)(ws + 2 * FB);
        float* ret = (float*)(ws + 3 * FB);
        float* sc  = (float*)(ws + 4 * FB);

        const dim3 gQKV(IDM / 64, (NB * LN) / 64);   // 16 x 256
        gemm_f32<0, 0><<<gQKV, blk, 0, stream>>>(i_in, q_w, nullptr, Q,  NB * LN, IDM, IDM);
        gemm_f32<0, 0><<<gQKV, blk, 0, stream>>>(i_in, k_w, nullptr, Kb, NB * LN, IDM, IDM);
        gemm_f32<0, 0><<<gQKV, blk, 0, stream>>>(i_in, v_w, nullptr, V,  NB * LN, IDM, IDM);

        for (int b = 0; b < NB; ++b) {
            const size_t boff = (size_t)b * LN * IDM;
            gemm_f32<1, 0><<<dim3(LN / 64, LN / 64), blk, 0, stream>>>(
                Q + boff, Kb + boff, nullptr, sc, LN, LN, IDM);
            softmax_rows<<<dim3(LN), blk, 0, stream>>>(sc);
            gemm_f32<0, 1><<<dim3(IDM / 64, LN / 64), blk, 0, stream>>>(
                sc, V + boff, i_in + boff, ret + boff, LN, IDM, LN);
        }
        gemm_f32<0, 2><<<dim3(ODM / 64, (NB * LN) / 64), blk, 0, stream>>>(
            ret, mlp_w, bias, out, NB * LN, ODM, IDM);
    } else {
        // ---- small path: fully per-batch (needs 4*PB + SB = 50 MiB) ----
        float* Qb  = (float*)(ws);
        float* Kb  = (float*)(ws + PB);
        float* Vb  = (float*)(ws + 2 * PB);
        float* rb  = (float*)(ws + 3 * PB);
        float* sc  = (float*)(ws + 4 * PB);

        const dim3 gQKV(IDM / 64, LN / 64);
        for (int b = 0; b < NB; ++b) {
            const size_t boff = (size_t)b * LN * IDM;
            gemm_f32<0, 0><<<gQKV, blk, 0, stream>>>(i_in + boff, q_w, nullptr, Qb, LN, IDM, IDM);
            gemm_f32<0, 0><<<gQKV, blk, 0, stream>>>(i_in + boff, k_w, nullptr, Kb, LN, IDM, IDM);
            gemm_f32<0, 0><<<gQKV, blk, 0, stream>>>(i_in + boff, v_w, nullptr, Vb, LN, IDM, IDM);
            gemm_f32<1, 0><<<dim3(LN / 64, LN / 64), blk, 0, stream>>>(
                Qb, Kb, nullptr, sc, LN, LN, IDM);
            softmax_rows<<<dim3(LN), blk, 0, stream>>>(sc);
            gemm_f32<0, 1><<<dim3(IDM / 64, LN / 64), blk, 0, stream>>>(
                sc, Vb, i_in + boff, rb, LN, IDM, LN);
            gemm_f32<0, 2><<<dim3(ODM / 64, LN / 64), blk, 0, stream>>>(
                rb, mlp_w, bias, out + (size_t)b * LN * ODM, LN, ODM, IDM);
        }
    }
}

// Round 3
// 3039.859 us; speedup vs baseline: 1.4289x; 1.4289x over previous
//
#include <hip/hip_runtime.h>
#include <hip/hip_bf16.h>
#include <math.h>

#define LN   2048
#define IDM  1024
#define NB   8
#define NEG_SLOPE 0.2f
#define LO_SCALE   4096.0f      // 2^12: keeps lo parts out of f16 denormal range
#define LO_INV     (1.0f/4096.0f)

typedef _Float16 f16x8 __attribute__((ext_vector_type(8)));
typedef float    f32x4 __attribute__((ext_vector_type(4)));

#define GLDS16(g, l) \
    __builtin_amdgcn_global_load_lds((const __attribute__((address_space(1))) void*)(g), \
                                     (__attribute__((address_space(3))) void*)(l), 16, 0, 0)

// ---------------------------------------------------------------------------
// Two-phase f16 MFMA GEMM (m97 structure: 128x128 tile, BK=32, 4 waves,
// global_load_lds w16, ds_read_b128, mfma_f32_16x16x32_f16).
// Phase 0 (optional, K2>0): acc += A2*B2^T, then acc *= 2^-12.
// Phase 1:                  acc += A1*B1^T.
// A: [M][K] f16 rows (stride lda).  B: [N][K] f16 rows (stride ldb).
// EPI: 0 = split store hi|lo   (C f16 [M][2N], hi at col, lo*2^12 at col+N)
//      1 = split store lo|hi
//      2 = f32 store [M][N]
//      3 = f16 transposed per-2048-row-batch store: VT[b][N][2048]
//      4 = f16 store of (acc + E_f32[M][N])
//      5 = f32 store of leaky_relu(acc) + E_f32[row&2047][N]
// ---------------------------------------------------------------------------
template<int EPI>
__global__ __launch_bounds__(256) void gemm2(
    const _Float16* __restrict__ A1, long long lda1, int K1,
    const _Float16* __restrict__ B1, long long ldb1,
    const _Float16* __restrict__ A2, long long lda2, int K2,
    const _Float16* __restrict__ B2, long long ldb2,
    const void* __restrict__ extraV, void* __restrict__ Cv,
    int M, int N,
    long long zsA, long long zsB, long long zsC, long long zsE)
{
    __shared__ _Float16 As[128 * 32];
    __shared__ _Float16 Bs[128 * 32];

    const int tid = threadIdx.x;
    const int z   = blockIdx.z;
    const int m0 = blockIdx.y * 128, n0 = blockIdx.x * 128;
    const int lane = tid & 63;
    const int w    = tid >> 6;
    const int wm = w & 1, wn = w >> 1;
    const int fr = lane & 15;
    const int fk = (lane >> 4) * 8;

    const int row0 = tid >> 2;        // 0..63
    const int kg   = (tid & 3) * 8;   // 0,8,16,24
    _Float16* lA0 = As + tid * 8;
    _Float16* lA1 = As + 2048 + tid * 8;
    _Float16* lB0 = Bs + tid * 8;
    _Float16* lB1 = Bs + 2048 + tid * 8;

    f32x4 acc[4][4] = {};

    #pragma unroll 1
    for (int ph = 0; ph < 2; ++ph) {
        const _Float16* A; const _Float16* B; long long lda, ldb; int K;
        if (ph == 0) {
            if (K2 == 0) continue;
            A = A2 + (size_t)z * zsA; B = B2 + (size_t)z * zsB;
            lda = lda2; ldb = ldb2; K = K2;
        } else {
            A = A1 + (size_t)z * zsA; B = B1 + (size_t)z * zsB;
            lda = lda1; ldb = ldb1; K = K1;
        }
        const _Float16* gA0 = A + (size_t)(m0 + row0) * lda + kg;
        const _Float16* gA1 = gA0 + (size_t)64 * lda;
        const _Float16* gB0 = B + (size_t)(n0 + row0) * ldb + kg;
        const _Float16* gB1 = gB0 + (size_t)64 * ldb;

        for (int k0 = 0; k0 < K; k0 += 32) {
            __syncthreads();
            GLDS16(gA0, lA0);
            GLDS16(gA1, lA1);
            GLDS16(gB0, lB0);
            GLDS16(gB1, lB1);
            gA0 += 32; gA1 += 32; gB0 += 32; gB1 += 32;
            __syncthreads();

            f16x8 aF[4], bF[4];
            #pragma unroll
            for (int mf = 0; mf < 4; ++mf)
                aF[mf] = *(const f16x8*)&As[(wm * 64 + mf * 16 + fr) * 32 + fk];
            #pragma unroll
            for (int nf = 0; nf < 4; ++nf)
                bF[nf] = *(const f16x8*)&Bs[(wn * 64 + nf * 16 + fr) * 32 + fk];
            #pragma unroll
            for (int mf = 0; mf < 4; ++mf)
                #pragma unroll
                for (int nf = 0; nf < 4; ++nf)
                    acc[mf][nf] = __builtin_amdgcn_mfma_f32_16x16x32_f16(aF[mf], bF[nf], acc[mf][nf], 0, 0, 0);
        }
        if (ph == 0) {
            #pragma unroll
            for (int mf = 0; mf < 4; ++mf)
                #pragma unroll
                for (int nf = 0; nf < 4; ++nf)
                    acc[mf][nf] *= LO_INV;
        }
    }

    // C/D layout: col = lane&15, row = (lane>>4)*4 + reg
    const int colb = n0 + wn * 64 + (lane & 15);
    const int rowb = m0 + wm * 64 + ((lane >> 4) * 4);

    if (EPI == 0 || EPI == 1) {
        _Float16* C = (_Float16*)Cv + (size_t)z * zsC;
        const long long ldc = 2 * (long long)N;
        #pragma unroll
        for (int mf = 0; mf < 4; ++mf)
            #pragma unroll
            for (int nf = 0; nf < 4; ++nf)
                #pragma unroll
                for (int r = 0; r < 4; ++r) {
                    const int row = rowb + mf * 16 + r;
                    const int col = colb + nf * 16;
                    float v = acc[mf][nf][r];
                    _Float16 h = (_Float16)v;
                    _Float16 l = (_Float16)((v - (float)h) * LO_SCALE);
                    if (EPI == 0) {
                        C[(size_t)row * ldc + col]     = h;
                        C[(size_t)row * ldc + N + col] = l;
                    } else {
                        C[(size_t)row * ldc + col]     = l;
                        C[(size_t)row * ldc + N + col] = h;
                    }
                }
    } else if (EPI == 2) {
        float* C = (float*)Cv + (size_t)z * zsC;
        #pragma unroll
        for (int mf = 0; mf < 4; ++mf)
            #pragma unroll
            for (int nf = 0; nf < 4; ++nf)
                #pragma unroll
                for (int r = 0; r < 4; ++r)
                    C[(size_t)(rowb + mf * 16 + r) * N + (colb + nf * 16)] = acc[mf][nf][r];
    } else if (EPI == 3) {
        _Float16* C = (_Float16*)Cv;   // VT: [batch][N][2048]
        #pragma unroll
        for (int mf = 0; mf < 4; ++mf) {
            const int row = rowb + mf * 16;
            const int bt = row >> 11, ml = row & 2047;
            #pragma unroll
            for (int nf = 0; nf < 4; ++nf) {
                union { _Float16 h[4]; short4 s4; } u;
                #pragma unroll
                for (int r = 0; r < 4; ++r) u.h[r] = (_Float16)acc[mf][nf][r];
                *(short4*)&C[(size_t)bt * N * 2048 + (size_t)(colb + nf * 16) * 2048 + ml] = u.s4;
            }
        }
    } else if (EPI == 4) {
        _Float16* C = (_Float16*)Cv + (size_t)z * zsC;
        const float* E = (const float*)extraV + (size_t)z * zsE;
        #pragma unroll
        for (int mf = 0; mf < 4; ++mf)
            #pragma unroll
            for (int nf = 0; nf < 4; ++nf)
                #pragma unroll
                for (int r = 0; r < 4; ++r) {
                    const size_t idx = (size_t)(rowb + mf * 16 + r) * N + (colb + nf * 16);
                    C[idx] = (_Float16)(acc[mf][nf][r] + E[idx]);
                }
    } else {  // EPI == 5
        float* C = (float*)Cv;
        const float* E = (const float*)extraV;
        #pragma unroll
        for (int mf = 0; mf < 4; ++mf)
            #pragma unroll
            for (int nf = 0; nf < 4; ++nf)
                #pragma unroll
                for (int r = 0; r < 4; ++r) {
                    const int row = rowb + mf * 16 + r;
                    const int col = colb + nf * 16;
                    float v = acc[mf][nf][r];
                    v = (v >= 0.f) ? v : NEG_SLOPE * v;
                    C[(size_t)row * N + col] = v + E[(size_t)(row & (LN - 1)) * N + col];
                }
    }
}

// ---------------------------------------------------------------------------
// i split: f32 [M][1024] -> f16 [M][2048]  (hi at cols 0-1023, lo*2^12 at 1024+)
__global__ __launch_bounds__(256) void split_i_k(
    const float* __restrict__ in, _Float16* __restrict__ out, long long n4)
{
    long long idx = (long long)blockIdx.x * 256 + threadIdx.x;
    if (idx >= n4) return;
    float4 v = ((const float4*)in)[idx];
    long long row = idx >> 8;          // 256 float4 per 1024-col row
    int c4 = (int)(idx & 255) * 4;
    union { _Float16 h[4]; short4 s4; } hi, lo;
    float f0 = v.x; _Float16 h0 = (_Float16)f0; hi.h[0] = h0; lo.h[0] = (_Float16)((f0 - (float)h0) * LO_SCALE);
    float f1 = v.y; _Float16 h1 = (_Float16)f1; hi.h[1] = h1; lo.h[1] = (_Float16)((f1 - (float)h1) * LO_SCALE);
    float f2 = v.z; _Float16 h2 = (_Float16)f2; hi.h[2] = h2; lo.h[2] = (_Float16)((f2 - (float)h2) * LO_SCALE);
    float f3 = v.w; _Float16 h3 = (_Float16)f3; hi.h[3] = h3; lo.h[3] = (_Float16)((f3 - (float)h3) * LO_SCALE);
    *(short4*)&out[row * 2048 + c4]        = hi.s4;
    *(short4*)&out[row * 2048 + 1024 + c4] = lo.s4;
}

// weight transpose+split: in [K=1024][N=1024] f32 -> out [N][2048] (lo*2^12 | hi)
__global__ __launch_bounds__(256) void split_wT_k(
    const float* __restrict__ in, _Float16* __restrict__ out)
{
    __shared__ float t[32][33];
    const int bx = blockIdx.x * 32, by = blockIdx.y * 32;
    const int tx = threadIdx.x & 31, ty = threadIdx.x >> 5;
    #pragma unroll
    for (int i = 0; i < 32; i += 8)
        t[ty + i][tx] = in[(size_t)(by + ty + i) * 1024 + (bx + tx)];
    __syncthreads();
    #pragma unroll
    for (int i = 0; i < 32; i += 8) {
        float f = t[tx][ty + i];              // = in[by+tx][bx+ty+i]
        _Float16 h = (_Float16)f;
        _Float16 l = (_Float16)((f - (float)h) * LO_SCALE);
        const size_t n = bx + ty + i, k = by + tx;
        out[n * 2048 + k]        = l;
        out[n * 2048 + 1024 + k] = h;
    }
}

// plain transpose+convert: in [K=1024][N=1024] f32 -> out [N][1024] f16
__global__ __launch_bounds__(256) void transp_f32_f16(
    const float* __restrict__ in, _Float16* __restrict__ out)
{
    __shared__ float t[32][33];
    const int bx = blockIdx.x * 32, by = blockIdx.y * 32;
    const int tx = threadIdx.x & 31, ty = threadIdx.x >> 5;
    #pragma unroll
    for (int i = 0; i < 32; i += 8)
        t[ty + i][tx] = in[(size_t)(by + ty + i) * 1024 + (bx + tx)];
    __syncthreads();
    #pragma unroll
    for (int i = 0; i < 32; i += 8)
        out[(size_t)(bx + ty + i) * 1024 + (by + tx)] = (_Float16)t[tx][ty + i];
}

// row softmax: S f32 [y-batch][2048] rows -> P f16
__global__ __launch_bounds__(256) void softmax_f32_f16(
    const float* __restrict__ S, _Float16* __restrict__ P)
{
    const int tid = threadIdx.x;
    const size_t base = (size_t)blockIdx.y * LN * LN + (size_t)blockIdx.x * LN;
    const float* row = S + base;
    _Float16* orow = P + base;

    float4 v0 = *(const float4*)&row[tid * 4];
    float4 v1 = *(const float4*)&row[1024 + tid * 4];

    float m = fmaxf(fmaxf(fmaxf(v0.x, v0.y), fmaxf(v0.z, v0.w)),
                    fmaxf(fmaxf(v1.x, v1.y), fmaxf(v1.z, v1.w)));
    #pragma unroll
    for (int off = 32; off > 0; off >>= 1) m = fmaxf(m, __shfl_xor(m, off));

    __shared__ float red[8];
    if ((tid & 63) == 0) red[tid >> 6] = m;
    __syncthreads();
    m = fmaxf(fmaxf(red[0], red[1]), fmaxf(red[2], red[3]));

    float e[8];
    e[0] = __expf(v0.x - m); e[1] = __expf(v0.y - m);
    e[2] = __expf(v0.z - m); e[3] = __expf(v0.w - m);
    e[4] = __expf(v1.x - m); e[5] = __expf(v1.y - m);
    e[6] = __expf(v1.z - m); e[7] = __expf(v1.w - m);
    float s = ((e[0] + e[1]) + (e[2] + e[3])) + ((e[4] + e[5]) + (e[6] + e[7]));
    #pragma unroll
    for (int off = 32; off > 0; off >>= 1) s += __shfl_xor(s, off);
    if ((tid & 63) == 0) red[4 + (tid >> 6)] = s;
    __syncthreads();
    s = (red[4] + red[5]) + (red[6] + red[7]);

    const float inv = 1.0f / s;
    union { _Float16 h[4]; short4 s4; } a, b;
    a.h[0] = (_Float16)(e[0] * inv); a.h[1] = (_Float16)(e[1] * inv);
    a.h[2] = (_Float16)(e[2] * inv); a.h[3] = (_Float16)(e[3] * inv);
    b.h[0] = (_Float16)(e[4] * inv); b.h[1] = (_Float16)(e[5] * inv);
    b.h[2] = (_Float16)(e[6] * inv); b.h[3] = (_Float16)(e[7] * inv);
    *(short4*)&orow[tid * 4] = a.s4;
    *(short4*)&orow[1024 + tid * 4] = b.s4;
}

// ---------------------------------------------------------------------------
extern "C" void kernel_launch(void* const* d_in, const int* in_sizes, int n_in,
                              void* d_out, int out_size, void* d_ws, size_t ws_size,
                              hipStream_t stream)
{
    (void)in_sizes; (void)n_in; (void)out_size;
    const float* i_in  = (const float*)d_in[0];
    const float* k_w   = (const float*)d_in[1];
    const float* q_w   = (const float*)d_in[2];
    const float* v_w   = (const float*)d_in[3];
    const float* mlp_w = (const float*)d_in[4];
    const float* bias  = (const float*)d_in[5];
    float* out = (float*)d_out;

    char* ws = (char*)d_ws;
    const dim3 blk(256);
    const dim3 tgrid(32, 32);

    const size_t CAT_F = (size_t)NB * LN * 2048 * sizeof(_Float16);   // 64 MiB
    const size_t WCT   = (size_t)1024 * 2048 * sizeof(_Float16);      //  4 MiB
    const size_t WT    = (size_t)1024 * 1024 * sizeof(_Float16);      //  2 MiB
    const size_t VTB   = (size_t)NB * IDM * LN * sizeof(_Float16);    // 32 MiB
    const size_t SCB   = (size_t)LN * LN * sizeof(float);             // 16 MiB
    const size_t ATB   = (size_t)LN * LN * sizeof(_Float16);          //  8 MiB

    const long long L2048 = 2048, L1024 = 1024;

    const size_t fixedB = 3 * CAT_F + VTB + 2 * WCT + 2 * WT;         // ~236 MiB
    if (ws_size >= fixedB + SCB + ATB) {
        // ================= big path =================
        _Float16* iCat  = (_Float16*)(ws);                 // [16384][2048] hi|lo
        _Float16* Qcat  = (_Float16*)(ws + CAT_F);         // [16384][2048] hi|lo
        _Float16* Kcat  = (_Float16*)(ws + 2 * CAT_F);     // [16384][2048] lo|hi
        _Float16* VT    = (_Float16*)(ws + 3 * CAT_F);     // [8][1024][2048]
        _Float16* qCatT = (_Float16*)(ws + 3 * CAT_F + VTB);
        _Float16* kCatT = (_Float16*)(ws + 3 * CAT_F + VTB + WCT);
        _Float16* vT    = (_Float16*)(ws + 3 * CAT_F + VTB + 2 * WCT);
        _Float16* mlpT  = (_Float16*)(ws + 3 * CAT_F + VTB + 2 * WCT + WT);
        char*     chnk  = ws + fixedB;
        _Float16* ret   = iCat;   // alias: iCat dead after V projection

        int CH = (int)((ws_size - fixedB) / (SCB + ATB));
        if (CH > NB) CH = NB;
        float*    sc  = (float*)chnk;
        _Float16* att = (_Float16*)(chnk + (size_t)CH * SCB);

        split_i_k<<<dim3(16384), blk, 0, stream>>>(i_in, iCat, (long long)NB * LN * IDM / 4);
        split_wT_k<<<tgrid, blk, 0, stream>>>(q_w, qCatT);
        split_wT_k<<<tgrid, blk, 0, stream>>>(k_w, kCatT);
        transp_f32_f16<<<tgrid, blk, 0, stream>>>(v_w, vT);
        transp_f32_f16<<<tgrid, blk, 0, stream>>>(mlp_w, mlpT);

        const dim3 gproj(8, 128);
        // Q = ihi*qhi + 2^-12*(ihi*qlo_s + ilo_s*qhi) -> split hi|lo
        gemm2<0><<<gproj, blk, 0, stream>>>(
            iCat, L2048, 1024, qCatT + 1024, L2048,
            iCat, L2048, 2048, qCatT, L2048,
            nullptr, Qcat, NB * LN, 1024, 0, 0, 0, 0);
        gemm2<1><<<gproj, blk, 0, stream>>>(
            iCat, L2048, 1024, kCatT + 1024, L2048,
            iCat, L2048, 2048, kCatT, L2048,
            nullptr, Kcat, NB * LN, 1024, 0, 0, 0, 0);
        // V = ihi * v  -> VT transposed per batch
        gemm2<3><<<gproj, blk, 0, stream>>>(
            iCat, L2048, 1024, vT, L1024,
            nullptr, 0, 0, nullptr, 0,
            nullptr, VT, NB * LN, 1024, 0, 0, 0, 0);

        for (int c0 = 0; c0 < NB; c0 += CH) {
            const int cur = (NB - c0 < CH) ? (NB - c0) : CH;
            const size_t coff = (size_t)c0 * LN * 2048;
            gemm2<2><<<dim3(16, 16, cur), blk, 0, stream>>>(
                Qcat + coff, L2048, 1024, Kcat + coff + 1024, L2048,
                Qcat + coff, L2048, 2048, Kcat + coff, L2048,
                nullptr, sc, LN, LN,
                (long long)LN * 2048, (long long)LN * 2048, (long long)LN * LN, 0);
            softmax_f32_f16<<<dim3(LN, cur), blk, 0, stream>>>(sc, att);
            gemm2<4><<<dim3(8, 16, cur), blk, 0, stream>>>(
                att, L2048, 2048, VT + (size_t)c0 * IDM * LN, L2048,
                nullptr, 0, 0, nullptr, 0,
                i_in + (size_t)c0 * LN * IDM, ret + (size_t)c0 * LN * IDM, LN, IDM,
                (long long)LN * LN, (long long)IDM * LN, (long long)LN * IDM, (long long)LN * IDM);
        }
        gemm2<5><<<dim3(8, 128), blk, 0, stream>>>(
            ret, L1024, 1024, mlpT, L1024,
            nullptr, 0, 0, nullptr, 0,
            bias, out, NB * LN, 1024, 0, 0, 0, 0);
    } else {
        // ================= small path (~52 MiB) =================
        _Float16* qCatT = (_Float16*)(ws);
        _Float16* kCatT = (_Float16*)(ws + WCT);
        _Float16* vT    = (_Float16*)(ws + 2 * WCT);
        _Float16* mlpT  = (_Float16*)(ws + 2 * WCT + WT);
        char* p = ws + 2 * WCT + 2 * WT;
        _Float16* iCat  = (_Float16*)(p);                          // [2048][2048]
        _Float16* Qcat  = (_Float16*)(p + (size_t)LN * 2048 * 2);
        _Float16* Kcat  = (_Float16*)(p + 2 * (size_t)LN * 2048 * 2);
        _Float16* VTb   = (_Float16*)(p + 3 * (size_t)LN * 2048 * 2);   // [1024][2048]
        float*    sc    = (float*)(p + 4 * (size_t)LN * 2048 * 2);      // [1024][2048] f32
        _Float16* att   = (_Float16*)(p + 4 * (size_t)LN * 2048 * 2 + (size_t)1024 * 2048 * 4);
        _Float16* ret   = iCat;   // alias after V proj

        split_wT_k<<<tgrid, blk, 0, stream>>>(q_w, qCatT);
        split_wT_k<<<tgrid, blk, 0, stream>>>(k_w, kCatT);
        transp_f32_f16<<<tgrid, blk, 0, stream>>>(v_w, vT);
        transp_f32_f16<<<tgrid, blk, 0, stream>>>(mlp_w, mlpT);

        for (int b = 0; b < NB; ++b) {
            const size_t boff = (size_t)b * LN * IDM;
            split_i_k<<<dim3(2048), blk, 0, stream>>>(i_in + boff, iCat, (long long)LN * IDM / 4);
            gemm2<0><<<dim3(8, 16), blk, 0, stream>>>(
                iCat, L2048, 1024, qCatT + 1024, L2048,
                iCat, L2048, 2048, qCatT, L2048,
                nullptr, Qcat, LN, 1024, 0, 0, 0, 0);
            gemm2<1><<<dim3(8, 16), blk, 0, stream>>>(
                iCat, L2048, 1024, kCatT + 1024, L2048,
                iCat, L2048, 2048, kCatT, L2048,
                nullptr, Kcat, LN, 1024, 0, 0, 0, 0);
            gemm2<3><<<dim3(8, 16), blk, 0, stream>>>(
                iCat, L2048, 1024, vT, L1024,
                nullptr, 0, 0, nullptr, 0,
                nullptr, VTb, LN, 1024, 0, 0, 0, 0);
            for (int rc = 0; rc < 2; ++rc) {
                const size_t roff = (size_t)rc * 1024;
                gemm2<2><<<dim3(16, 8), blk, 0, stream>>>(
                    Qcat + roff * 2048, L2048, 1024, Kcat + 1024, L2048,
                    Qcat + roff * 2048, L2048, 2048, Kcat, L2048,
                    nullptr, sc, 1024, LN, 0, 0, 0, 0);
                softmax_f32_f16<<<dim3(1024, 1), blk, 0, stream>>>(sc, att);
                gemm2<4><<<dim3(8, 8), blk, 0, stream>>>(
                    att, L2048, 2048, VTb, L2048,
                    nullptr, 0, 0, nullptr, 0,
                    i_in + boff + roff * 1024, ret + roff * 1024, 1024, IDM, 0, 0, 0, 0);
            }
            gemm2<5><<<dim3(8, 16), blk, 0, stream>>>(
                ret, L1024, 1024, mlpT, L1024,
                nullptr, 0, 0, nullptr, 0,
                bias, out + boff, LN, 1024, 0, 0, 0, 0);
        }
    }
}

// Round 4
// 748.206 us; speedup vs baseline: 5.8056x; 4.0629x over previous
//
#include <hip/hip_runtime.h>
#include <hip/hip_bf16.h>
#include <math.h>

#define LN   2048
#define IDM  1024
#define NB   8
#define NEG_SLOPE 0.2f
#define LO_SCALE   4096.0f      // 2^12: keeps lo parts out of f16 denormal range
#define LO_INV     (1.0f/4096.0f)

typedef _Float16 f16x8 __attribute__((ext_vector_type(8)));
typedef float    f32x4 __attribute__((ext_vector_type(4)));

#define GLDS16(g, l) \
    __builtin_amdgcn_global_load_lds((const __attribute__((address_space(1))) void*)(g), \
                                     (__attribute__((address_space(3))) void*)(l), 16, 0, 0)

extern __shared__ char smem[];   // 128 KiB dynamic LDS: 2 bufs x (A 32K + B 32K)

// ---------------------------------------------------------------------------
// 256x256 tile, BK=64, 8 waves (2M x 4N), double-buffered LDS, counted vmcnt,
// st-swizzled LDS (byte ^= (row&7)<<4), setprio around MFMA, 2-segment K.
// Segment order: (A2,B2,K2) first (correction), then acc *= 2^-12, then (A1,B1,K1).
// A: [M][K] f16 rows (stride lda).  B: [N][K] f16 rows (stride ldb).
// EPI: 0 = split store hi|lo  (C f16 [M][2N]) ; 1 = split store lo|hi
//      2 = f32 store [M][N]
//      3 = f16 transposed per-2048-row-batch store: VT[b][N][2048]
//      4 = f16 store of (acc + E_f32[M][N])
//      5 = f32 store of leaky_relu(acc) + E_f32[row&2047][N]
// ---------------------------------------------------------------------------
template<int EPI>
__global__ __launch_bounds__(512, 2) void gemm256(
    const _Float16* __restrict__ A1, long long lda1, int K1,
    const _Float16* __restrict__ B1, long long ldb1,
    const _Float16* __restrict__ A2, long long lda2, int K2,
    const _Float16* __restrict__ B2, long long ldb2,
    const void* __restrict__ extraV, void* __restrict__ Cv,
    int M, int N,
    long long zsA, long long zsB, long long zsC, long long zsE)
{
    const int tid  = threadIdx.x;
    const int z    = blockIdx.z;
    const int m0   = blockIdx.y * 256, n0 = blockIdx.x * 256;
    const int lane = tid & 63;
    const int wid  = tid >> 6;
    const int wm   = wid >> 2;        // 0..1  (M half)
    const int wn   = wid & 3;         // 0..3  (N quarter)

    // staging constants: thread covers 16B at dest D = is*8192 + tid*16
    const int rA   = tid >> 3;                              // dest row 0..63 (+64*is)
    const int cF   = (((tid & 7) << 4) ^ ((rA & 7) << 4)) >> 1;  // pre-swizzled src col (f16)

    const int NT2 = K2 >> 6;
    const int NT  = NT2 + (K1 >> 6);

    const _Float16* A1z = A1 + (size_t)z * zsA;
    const _Float16* B1z = B1 + (size_t)z * zsB;
    const _Float16* A2z = (K2 > 0) ? A2 + (size_t)z * zsA : A1z;
    const _Float16* B2z = (K2 > 0) ? B2 + (size_t)z * zsB : B1z;

    auto stage = [&](int t) {
        const _Float16* As; const _Float16* Bs; long long la, lb; int kk;
        if (t < NT2) { As = A2z; Bs = B2z; la = lda2; lb = ldb2; kk = t << 6; }
        else         { As = A1z; Bs = B1z; la = lda1; lb = ldb1; kk = (t - NT2) << 6; }
        char* base = smem + (size_t)(t & 1) * 65536;
        #pragma unroll
        for (int is = 0; is < 4; ++is) {
            GLDS16(As + (size_t)(m0 + rA + is * 64) * la + kk + cF,
                   base + is * 8192 + tid * 16);
            GLDS16(Bs + (size_t)(n0 + rA + is * 64) * lb + kk + cF,
                   base + 32768 + is * 8192 + tid * 16);
        }
    };

    f32x4 acc[8][4] = {};

    stage(0);
    if (NT > 1) stage(1);

    #pragma unroll 1
    for (int t = 0; t < NT; ++t) {
        if (t < NT - 1) { asm volatile("s_waitcnt vmcnt(8)" ::: "memory"); }
        else            { asm volatile("s_waitcnt vmcnt(0)" ::: "memory"); }
        __builtin_amdgcn_s_barrier();
        __builtin_amdgcn_sched_barrier(0);

        const char* buf = smem + (size_t)(t & 1) * 65536;
        const int sw = (lane & 7) << 4;
        #pragma unroll
        for (int ks = 0; ks < 2; ++ks) {
            const int kb = ks * 64 + ((lane >> 4) << 4);   // byte col in row
            f16x8 aF[8], bF[4];
            #pragma unroll
            for (int mf = 0; mf < 8; ++mf) {
                const int row = wm * 128 + mf * 16 + (lane & 15);
                aF[mf] = *(const f16x8*)(buf + ((row * 128 + kb) ^ sw));
            }
            #pragma unroll
            for (int nf = 0; nf < 4; ++nf) {
                const int row = wn * 64 + nf * 16 + (lane & 15);
                bF[nf] = *(const f16x8*)(buf + 32768 + ((row * 128 + kb) ^ sw));
            }
            __builtin_amdgcn_s_setprio(1);
            #pragma unroll
            for (int mf = 0; mf < 8; ++mf)
                #pragma unroll
                for (int nf = 0; nf < 4; ++nf)
                    acc[mf][nf] = __builtin_amdgcn_mfma_f32_16x16x32_f16(aF[mf], bF[nf], acc[mf][nf], 0, 0, 0);
            __builtin_amdgcn_s_setprio(0);
        }

        if (t == NT2 - 1) {
            #pragma unroll
            for (int mf = 0; mf < 8; ++mf)
                #pragma unroll
                for (int nf = 0; nf < 4; ++nf)
                    acc[mf][nf] *= LO_INV;
        }

        __builtin_amdgcn_sched_barrier(0);
        __builtin_amdgcn_s_barrier();
        if (t + 2 < NT) stage(t + 2);
    }

    // C/D layout: col = lane&15, row = (lane>>4)*4 + reg
    const int colb = n0 + wn * 64 + (lane & 15);
    const int rowb = m0 + wm * 128 + ((lane >> 4) << 2);

    if (EPI == 0 || EPI == 1) {
        _Float16* C = (_Float16*)Cv + (size_t)z * zsC;
        const long long ldc = 2 * (long long)N;
        #pragma unroll
        for (int mf = 0; mf < 8; ++mf)
            #pragma unroll
            for (int nf = 0; nf < 4; ++nf)
                #pragma unroll
                for (int r = 0; r < 4; ++r) {
                    const int row = rowb + mf * 16 + r;
                    const int col = colb + nf * 16;
                    float v = acc[mf][nf][r];
                    _Float16 h = (_Float16)v;
                    _Float16 l = (_Float16)((v - (float)h) * LO_SCALE);
                    if (EPI == 0) {
                        C[(size_t)row * ldc + col]     = h;
                        C[(size_t)row * ldc + N + col] = l;
                    } else {
                        C[(size_t)row * ldc + col]     = l;
                        C[(size_t)row * ldc + N + col] = h;
                    }
                }
    } else if (EPI == 2) {
        float* C = (float*)Cv + (size_t)z * zsC;
        #pragma unroll
        for (int mf = 0; mf < 8; ++mf)
            #pragma unroll
            for (int nf = 0; nf < 4; ++nf)
                #pragma unroll
                for (int r = 0; r < 4; ++r)
                    C[(size_t)(rowb + mf * 16 + r) * N + (colb + nf * 16)] = acc[mf][nf][r];
    } else if (EPI == 3) {
        _Float16* C = (_Float16*)Cv;   // VT: [batch][N][2048]
        #pragma unroll
        for (int mf = 0; mf < 8; ++mf) {
            const int row = rowb + mf * 16;
            const int bt = row >> 11, ml = row & 2047;
            #pragma unroll
            for (int nf = 0; nf < 4; ++nf) {
                union { _Float16 h[4]; short4 s4; } u;
                #pragma unroll
                for (int r = 0; r < 4; ++r) u.h[r] = (_Float16)acc[mf][nf][r];
                *(short4*)&C[(size_t)bt * (size_t)IDM * 2048 + (size_t)(colb + nf * 16) * 2048 + ml] = u.s4;
            }
        }
    } else if (EPI == 4) {
        _Float16* C = (_Float16*)Cv + (size_t)z * zsC;
        const float* E = (const float*)extraV + (size_t)z * zsE;
        #pragma unroll
        for (int mf = 0; mf < 8; ++mf)
            #pragma unroll
            for (int nf = 0; nf < 4; ++nf)
                #pragma unroll
                for (int r = 0; r < 4; ++r) {
                    const size_t idx = (size_t)(rowb + mf * 16 + r) * N + (colb + nf * 16);
                    C[idx] = (_Float16)(acc[mf][nf][r] + E[idx]);
                }
    } else {  // EPI == 5
        float* C = (float*)Cv;
        const float* E = (const float*)extraV;
        #pragma unroll
        for (int mf = 0; mf < 8; ++mf)
            #pragma unroll
            for (int nf = 0; nf < 4; ++nf)
                #pragma unroll
                for (int r = 0; r < 4; ++r) {
                    const int row = rowb + mf * 16 + r;
                    const int col = colb + nf * 16;
                    float v = acc[mf][nf][r];
                    v = (v >= 0.f) ? v : NEG_SLOPE * v;
                    C[(size_t)row * N + col] = v + E[(size_t)(row & (LN - 1)) * N + col];
                }
    }
}

// ---------------------------------------------------------------------------
// i split: f32 [M][1024] -> f16 [M][2048]  (hi | lo*2^12)
__global__ __launch_bounds__(256) void split_i_k(
    const float* __restrict__ in, _Float16* __restrict__ out, long long n4)
{
    long long idx = (long long)blockIdx.x * 256 + threadIdx.x;
    if (idx >= n4) return;
    float4 v = ((const float4*)in)[idx];
    long long row = idx >> 8;
    int c4 = (int)(idx & 255) * 4;
    union { _Float16 h[4]; short4 s4; } hi, lo;
    float f0 = v.x; _Float16 h0 = (_Float16)f0; hi.h[0] = h0; lo.h[0] = (_Float16)((f0 - (float)h0) * LO_SCALE);
    float f1 = v.y; _Float16 h1 = (_Float16)f1; hi.h[1] = h1; lo.h[1] = (_Float16)((f1 - (float)h1) * LO_SCALE);
    float f2 = v.z; _Float16 h2 = (_Float16)f2; hi.h[2] = h2; lo.h[2] = (_Float16)((f2 - (float)h2) * LO_SCALE);
    float f3 = v.w; _Float16 h3 = (_Float16)f3; hi.h[3] = h3; lo.h[3] = (_Float16)((f3 - (float)h3) * LO_SCALE);
    *(short4*)&out[row * 2048 + c4]        = hi.s4;
    *(short4*)&out[row * 2048 + 1024 + c4] = lo.s4;
}

// weight transpose+split: in [K=1024][N=1024] f32 -> out [N][2048] (lo*2^12 | hi)
__global__ __launch_bounds__(256) void split_wT_k(
    const float* __restrict__ in, _Float16* __restrict__ out)
{
    __shared__ float t[32][33];
    const int bx = blockIdx.x * 32, by = blockIdx.y * 32;
    const int tx = threadIdx.x & 31, ty = threadIdx.x >> 5;
    #pragma unroll
    for (int i = 0; i < 32; i += 8)
        t[ty + i][tx] = in[(size_t)(by + ty + i) * 1024 + (bx + tx)];
    __syncthreads();
    #pragma unroll
    for (int i = 0; i < 32; i += 8) {
        float f = t[tx][ty + i];
        _Float16 h = (_Float16)f;
        _Float16 l = (_Float16)((f - (float)h) * LO_SCALE);
        const size_t n = bx + ty + i, k = by + tx;
        out[n * 2048 + k]        = l;
        out[n * 2048 + 1024 + k] = h;
    }
}

// plain transpose+convert: in [K=1024][N=1024] f32 -> out [N][1024] f16
__global__ __launch_bounds__(256) void transp_f32_f16(
    const float* __restrict__ in, _Float16* __restrict__ out)
{
    __shared__ float t[32][33];
    const int bx = blockIdx.x * 32, by = blockIdx.y * 32;
    const int tx = threadIdx.x & 31, ty = threadIdx.x >> 5;
    #pragma unroll
    for (int i = 0; i < 32; i += 8)
        t[ty + i][tx] = in[(size_t)(by + ty + i) * 1024 + (bx + tx)];
    __syncthreads();
    #pragma unroll
    for (int i = 0; i < 32; i += 8)
        out[(size_t)(bx + ty + i) * 1024 + (by + tx)] = (_Float16)t[tx][ty + i];
}

// in-place row softmax: S f32 row -> f16 written over the row's first half.
// All global reads complete before the first __syncthreads -> in-place safe.
__global__ __launch_bounds__(256) void softmax_ip(float* __restrict__ S)
{
    const int tid = threadIdx.x;
    float* row = S + (size_t)blockIdx.y * LN * LN + (size_t)blockIdx.x * LN;

    float4 v0 = *(const float4*)&row[tid * 4];
    float4 v1 = *(const float4*)&row[1024 + tid * 4];

    float m = fmaxf(fmaxf(fmaxf(v0.x, v0.y), fmaxf(v0.z, v0.w)),
                    fmaxf(fmaxf(v1.x, v1.y), fmaxf(v1.z, v1.w)));
    #pragma unroll
    for (int off = 32; off > 0; off >>= 1) m = fmaxf(m, __shfl_xor(m, off));

    __shared__ float red[8];
    if ((tid & 63) == 0) red[tid >> 6] = m;
    __syncthreads();
    m = fmaxf(fmaxf(red[0], red[1]), fmaxf(red[2], red[3]));

    float e[8];
    e[0] = __expf(v0.x - m); e[1] = __expf(v0.y - m);
    e[2] = __expf(v0.z - m); e[3] = __expf(v0.w - m);
    e[4] = __expf(v1.x - m); e[5] = __expf(v1.y - m);
    e[6] = __expf(v1.z - m); e[7] = __expf(v1.w - m);
    float s = ((e[0] + e[1]) + (e[2] + e[3])) + ((e[4] + e[5]) + (e[6] + e[7]));
    #pragma unroll
    for (int off = 32; off > 0; off >>= 1) s += __shfl_xor(s, off);
    if ((tid & 63) == 0) red[4 + (tid >> 6)] = s;
    __syncthreads();
    s = (red[4] + red[5]) + (red[6] + red[7]);

    const float inv = 1.0f / s;
    _Float16* orow = (_Float16*)row;
    union { _Float16 h[4]; short4 s4; } a, b;
    a.h[0] = (_Float16)(e[0] * inv); a.h[1] = (_Float16)(e[1] * inv);
    a.h[2] = (_Float16)(e[2] * inv); a.h[3] = (_Float16)(e[3] * inv);
    b.h[0] = (_Float16)(e[4] * inv); b.h[1] = (_Float16)(e[5] * inv);
    b.h[2] = (_Float16)(e[6] * inv); b.h[3] = (_Float16)(e[7] * inv);
    *(short4*)&orow[tid * 4] = a.s4;
    *(short4*)&orow[1024 + tid * 4] = b.s4;
}

// ---------------------------------------------------------------------------
extern "C" void kernel_launch(void* const* d_in, const int* in_sizes, int n_in,
                              void* d_out, int out_size, void* d_ws, size_t ws_size,
                              hipStream_t stream)
{
    (void)in_sizes; (void)n_in; (void)out_size;
    const float* i_in  = (const float*)d_in[0];
    const float* k_w   = (const float*)d_in[1];
    const float* q_w   = (const float*)d_in[2];
    const float* v_w   = (const float*)d_in[3];
    const float* mlp_w = (const float*)d_in[4];
    const float* bias  = (const float*)d_in[5];
    float* out = (float*)d_out;

    // allow >64 KiB dynamic LDS (ignore errors; harmless host-side calls)
    (void)hipFuncSetAttribute((const void*)gemm256<0>, hipFuncAttributeMaxDynamicSharedMemorySize, 131072);
    (void)hipFuncSetAttribute((const void*)gemm256<1>, hipFuncAttributeMaxDynamicSharedMemorySize, 131072);
    (void)hipFuncSetAttribute((const void*)gemm256<2>, hipFuncAttributeMaxDynamicSharedMemorySize, 131072);
    (void)hipFuncSetAttribute((const void*)gemm256<3>, hipFuncAttributeMaxDynamicSharedMemorySize, 131072);
    (void)hipFuncSetAttribute((const void*)gemm256<4>, hipFuncAttributeMaxDynamicSharedMemorySize, 131072);
    (void)hipFuncSetAttribute((const void*)gemm256<5>, hipFuncAttributeMaxDynamicSharedMemorySize, 131072);

    char* ws = (char*)d_ws;
    const dim3 blk512(512);
    const dim3 blk256(256);
    const dim3 tgrid(32, 32);
    const size_t LDSB = 131072;

    const size_t MiB = 1ull << 20;
    const long long L2048 = 2048, L1024 = 1024, L4096 = 4096;

    // big-path layout (236 MiB):
    //  [0,64)    Qcat  f16 [16384][2048] hi|lo   (first 32 MiB reused as ret)
    //  [64,128)  Kcat  f16 [16384][2048] lo|hi
    //  [128,160) VT    f16 [8][1024][2048]
    //  [160,172) qCatT, kCatT (4 each), vT, mlpT (2 each)
    //  [172,236) iCat  f16 [16384][2048]  (dead after V-proj; reused as sc chunk)
    if (ws_size >= 236 * MiB) {
        _Float16* Qcat  = (_Float16*)(ws);
        _Float16* Kcat  = (_Float16*)(ws + 64 * MiB);
        _Float16* VT    = (_Float16*)(ws + 128 * MiB);
        _Float16* qCatT = (_Float16*)(ws + 160 * MiB);
        _Float16* kCatT = (_Float16*)(ws + 164 * MiB);
        _Float16* vT    = (_Float16*)(ws + 168 * MiB);
        _Float16* mlpT  = (_Float16*)(ws + 170 * MiB);
        _Float16* iCat  = (_Float16*)(ws + 172 * MiB);
        float*    sc    = (float*)(ws + 172 * MiB);     // 4 batches x 16 MiB
        _Float16* ret   = Qcat;                          // [16384][1024], 32 MiB

        split_i_k<<<dim3(16384), blk256, 0, stream>>>(i_in, iCat, (long long)NB * LN * IDM / 4);
        split_wT_k<<<tgrid, blk256, 0, stream>>>(q_w, qCatT);
        split_wT_k<<<tgrid, blk256, 0, stream>>>(k_w, kCatT);
        transp_f32_f16<<<tgrid, blk256, 0, stream>>>(v_w, vT);
        transp_f32_f16<<<tgrid, blk256, 0, stream>>>(mlp_w, mlpT);

        const dim3 gproj(4, 64);
        gemm256<0><<<gproj, blk512, LDSB, stream>>>(
            iCat, L2048, 1024, qCatT + 1024, L2048,
            iCat, L2048, 2048, qCatT, L2048,
            nullptr, Qcat, NB * LN, 1024, 0, 0, 0, 0);
        gemm256<1><<<gproj, blk512, LDSB, stream>>>(
            iCat, L2048, 1024, kCatT + 1024, L2048,
            iCat, L2048, 2048, kCatT, L2048,
            nullptr, Kcat, NB * LN, 1024, 0, 0, 0, 0);
        gemm256<3><<<gproj, blk512, LDSB, stream>>>(
            iCat, L2048, 1024, vT, L1024,
            nullptr, 0, 0, nullptr, 0,
            nullptr, VT, NB * LN, 1024, 0, 0, 0, 0);
        // iCat now dead; sc aliases it.

        for (int c = 0; c < 2; ++c) {
            const size_t coff = (size_t)c * 4 * LN * 2048;     // f16 elems into Qcat/Kcat
            gemm256<2><<<dim3(8, 8, 4), blk512, LDSB, stream>>>(
                Qcat + coff, L2048, 1024, Kcat + coff + 1024, L2048,
                Qcat + coff, L2048, 2048, Kcat + coff, L2048,
                nullptr, sc, LN, LN,
                (long long)LN * 2048, (long long)LN * 2048, (long long)LN * LN, 0);
            softmax_ip<<<dim3(LN, 4), blk256, 0, stream>>>(sc);
            // att = f16 rows inside sc: row stride 4096 f16, batch stride LN*LN*2 f16
            gemm256<4><<<dim3(4, 8, 4), blk512, LDSB, stream>>>(
                (const _Float16*)sc, L4096, 2048, VT + (size_t)c * 4 * IDM * LN, L2048,
                nullptr, 0, 0, nullptr, 0,
                i_in + (size_t)c * 4 * LN * IDM, ret + (size_t)c * 4 * LN * IDM,
                LN, IDM,
                (long long)LN * LN * 2, (long long)IDM * LN, (long long)LN * IDM, (long long)LN * IDM);
        }
        gemm256<5><<<dim3(4, 64), blk512, LDSB, stream>>>(
            ret, L1024, 1024, mlpT, L1024,
            nullptr, 0, 0, nullptr, 0,
            bias, out, NB * LN, 1024, 0, 0, 0, 0);
    } else {
        // -------- small path (~60 MiB), per batch --------
        _Float16* qCatT = (_Float16*)(ws);
        _Float16* kCatT = (_Float16*)(ws + 4 * MiB);
        _Float16* vT    = (_Float16*)(ws + 8 * MiB);
        _Float16* mlpT  = (_Float16*)(ws + 10 * MiB);
        _Float16* iCat  = (_Float16*)(ws + 12 * MiB);   // [2048][2048]
        _Float16* Qcat  = (_Float16*)(ws + 20 * MiB);
        _Float16* Kcat  = (_Float16*)(ws + 28 * MiB);
        _Float16* VTb   = (_Float16*)(ws + 36 * MiB);   // [1024][2048]
        float*    sc    = (float*)(ws + 40 * MiB);      // [2048][2048] f32
        _Float16* ret   = (_Float16*)(ws + 56 * MiB);   // [2048][1024]

        split_wT_k<<<tgrid, blk256, 0, stream>>>(q_w, qCatT);
        split_wT_k<<<tgrid, blk256, 0, stream>>>(k_w, kCatT);
        transp_f32_f16<<<tgrid, blk256, 0, stream>>>(v_w, vT);
        transp_f32_f16<<<tgrid, blk256, 0, stream>>>(mlp_w, mlpT);

        for (int b = 0; b < NB; ++b) {
            const size_t boff = (size_t)b * LN * IDM;
            split_i_k<<<dim3(2048), blk256, 0, stream>>>(i_in + boff, iCat, (long long)LN * IDM / 4);
            gemm256<0><<<dim3(4, 8), blk512, LDSB, stream>>>(
                iCat, L2048, 1024, qCatT + 1024, L2048,
                iCat, L2048, 2048, qCatT, L2048,
                nullptr, Qcat, LN, 1024, 0, 0, 0, 0);
            gemm256<1><<<dim3(4, 8), blk512, LDSB, stream>>>(
                iCat, L2048, 1024, kCatT + 1024, L2048,
                iCat, L2048, 2048, kCatT, L2048,
                nullptr, Kcat, LN, 1024, 0, 0, 0, 0);
            gemm256<3><<<dim3(4, 8), blk512, LDSB, stream>>>(
                iCat, L2048, 1024, vT, L1024,
                nullptr, 0, 0, nullptr, 0,
                nullptr, VTb, LN, 1024, 0, 0, 0, 0);
            gemm256<2><<<dim3(8, 8), blk512, LDSB, stream>>>(
                Qcat, L2048, 1024, Kcat + 1024, L2048,
                Qcat, L2048, 2048, Kcat, L2048,
                nullptr, sc, LN, LN, 0, 0, 0, 0);
            softmax_ip<<<dim3(LN, 1), blk256, 0, stream>>>(sc);
            gemm256<4><<<dim3(4, 8), blk512, LDSB, stream>>>(
                (const _Float16*)sc, L4096, 2048, VTb, L2048,
                nullptr, 0, 0, nullptr, 0,
                i_in + boff, ret, LN, IDM, 0, 0, 0, 0);
            gemm256<5><<<dim3(4, 8), blk512, LDSB, stream>>>(
                ret, L1024, 1024, mlpT, L1024,
                nullptr, 0, 0, nullptr, 0,
                bias, out + boff, LN, 1024, 0, 0, 0, 0);
        }
    }
}